// Round 10
// baseline (96.155 us; speedup 1.0000x reference)
//
#include <hip/hip_runtime.h>
#include <math.h>

// AttentionContextEncoder on MI355X — R9b: full moment factorization, no LDS.
// tanh3(x)=x+C3*x^3, x = a_i - p_j + w4*d_ij.  Sum_j x^3 = cubic in a_i with
// coefficients from per-i geometric moments dotted with per-h weight forms:
//   M_a = g_i.w, M_b = w^T G_i w, M_c = h_i.w, P2 = w^T S w, P3 = T(w,w,w).
// KA: per-batch pair loop -> moments in ws.  KB: per-(i,h) epilogue, LDS-free.
// (R9 failed to compile: __sqrtf is CUDA-only; use sqrtf.)

#define NUM_ENT 64
#define HALF    128
#define BATCH   512
#define HDR     48                    // header floats (E4,S10,T20 + pad)
#define RECF    28                    // per-i record floats (e4,g4,h4,D3,G10,pad)
#define BSTRIDE (HDR + NUM_ENT * RECF)   // 1840 floats per batch

__device__ __forceinline__ float tanh5(float x) {
    float x2 = x * x;
    return x * fmaf(x2, fmaf(x2, 0.13333334f, -0.33333334f), 1.0f);
}
__device__ __forceinline__ float rdlane(float v, int k) {
    return __uint_as_float(__builtin_amdgcn_readlane(__float_as_uint(v), k));
}

// ---- KA: one wave per batch. lane = entity i. ----
__global__ __launch_bounds__(64) void ka_moments(const float* __restrict__ ctx,
                                                 float* __restrict__ ws)
{
    const int b = blockIdx.x, i = threadIdx.x;

    const float e0 = ctx[(size_t)(i * 4 + 0) * BATCH + b];
    const float e1 = ctx[(size_t)(i * 4 + 1) * BATCH + b];
    const float e2 = ctx[(size_t)(i * 4 + 2) * BATCH + b];
    const float e3 = ctx[(size_t)(i * 4 + 3) * BATCH + b];

    float D1 = 0.f, D2 = 0.f, D3 = 0.f;
    float g0 = 0.f, g1 = 0.f, g2 = 0.f, g3 = 0.f;
    float h0 = 0.f, h1 = 0.f, h2 = 0.f, h3 = 0.f;
    float G[10] = {0,0,0,0,0,0,0,0,0,0};

    #pragma unroll 8
    for (int k = 0; k < NUM_ENT; ++k) {
        // e_k broadcast to SGPRs (scalar VALU operands, no LDS/shuffle pipe)
        float s0 = rdlane(e0, k), s1 = rdlane(e1, k);
        float s2 = rdlane(e2, k), s3 = rdlane(e3, k);
        float dx = e0 - s0, dy = e1 - s1;
        float d2 = fmaf(dx, dx, dy * dy);
        float d  = sqrtf(d2);                // exact 0 at k==i
        D1 += d; D2 += d2; D3 = fmaf(d, d2, D3);
        float t0 = d * s0, t1 = d * s1, t2 = d * s2, t3 = d * s3;
        g0 += t0; g1 += t1; g2 += t2; g3 += t3;
        h0 = fmaf(d2, s0, h0); h1 = fmaf(d2, s1, h1);
        h2 = fmaf(d2, s2, h2); h3 = fmaf(d2, s3, h3);
        G[0] = fmaf(t0, s0, G[0]); G[1] = fmaf(t0, s1, G[1]);
        G[2] = fmaf(t0, s2, G[2]); G[3] = fmaf(t0, s3, G[3]);
        G[4] = fmaf(t1, s1, G[4]); G[5] = fmaf(t1, s2, G[5]);
        G[6] = fmaf(t1, s3, G[6]); G[7] = fmaf(t2, s2, G[7]);
        G[8] = fmaf(t2, s3, G[8]); G[9] = fmaf(t3, s3, G[9]);
    }

    // batch moments E(4), S(10), T(20) from lane-local e via butterfly
    float m[34];
    m[0] = e0; m[1] = e1; m[2] = e2; m[3] = e3;
    float u[10] = { e0*e0, e0*e1, e0*e2, e0*e3, e1*e1,
                    e1*e2, e1*e3, e2*e2, e2*e3, e3*e3 };
    #pragma unroll
    for (int k = 0; k < 10; ++k) m[4 + k] = u[k];
    m[14] = u[0]*e0; m[15] = u[0]*e1; m[16] = u[0]*e2; m[17] = u[0]*e3;
    m[18] = u[1]*e1; m[19] = u[1]*e2; m[20] = u[1]*e3;
    m[21] = u[2]*e2; m[22] = u[2]*e3; m[23] = u[3]*e3;
    m[24] = u[4]*e1; m[25] = u[4]*e2; m[26] = u[4]*e3;
    m[27] = u[5]*e2; m[28] = u[5]*e3; m[29] = u[6]*e3;
    m[30] = u[7]*e2; m[31] = u[7]*e3; m[32] = u[8]*e3; m[33] = u[9]*e3;
    #pragma unroll
    for (int s = 1; s < 64; s <<= 1)
        #pragma unroll
        for (int k = 0; k < 34; ++k) m[k] += __shfl_xor(m[k], s);

    float* wb = ws + (size_t)b * BSTRIDE;
    if (i == 0) {
        #pragma unroll
        for (int k = 0; k < 34; ++k) wb[k] = m[k];
    }
    float4* rec = (float4*)(wb + HDR + i * RECF);
    rec[0] = make_float4(e0, e1, e2, e3);
    rec[1] = make_float4(g0, g1, g2, g3);
    rec[2] = make_float4(h0, h1, h2, h3);
    rec[3] = make_float4(D1, D2, D3, G[0]);
    rec[4] = make_float4(G[1], G[2], G[3], G[4]);
    rec[5] = make_float4(G[5], G[6], G[7], G[8]);
    rec[6] = make_float4(G[9], 0.f, 0.f, 0.f);
}

// ---- KB: one block per batch; thread = (h, i-half); LDS-free. ----
__global__ __launch_bounds__(256) void kb_out(
    const float* __restrict__ ws,  const float* __restrict__ Wp,
    const float* __restrict__ bp,  const float* __restrict__ Wr,
    const float* __restrict__ br,  float* __restrict__ out)
{
    const int b = blockIdx.x, t = threadIdx.x;
    const int h = t & 127;
    const int ihalf = __builtin_amdgcn_readfirstlane(t >> 7);  // wave-uniform

    const float w0 = Wr[h],          w1 = Wr[HALF + h];
    const float w2 = Wr[2*HALF + h], w3 = Wr[3*HALF + h];
    const float w4 = Wr[4*HALF + h], bb = br[h];
    const float q0 = Wp[h],          q1 = Wp[HALF + h];
    const float q2 = Wp[2*HALF + h], q3 = Wp[3*HALF + h];
    const float bq = bp[h];

    const float* hd = ws + (size_t)b * BSTRIDE;   // uniform -> s_load
    // weight pair forms: raw and mult2-folded
    const float W2r[10] = { w0*w0, w0*w1, w0*w2, w0*w3, w1*w1,
                            w1*w2, w1*w3, w2*w2, w2*w3, w3*w3 };
    float W2m[10];
    #pragma unroll
    for (int k = 0; k < 10; ++k) W2m[k] = W2r[k];
    W2m[1] *= 2.f; W2m[2] *= 2.f; W2m[3] *= 2.f;
    W2m[5] *= 2.f; W2m[6] *= 2.f; W2m[8] *= 2.f;

    const float P1 = fmaf(hd[0], w0, fmaf(hd[1], w1,
                     fmaf(hd[2], w2, hd[3] * w3)));
    float P2 = 0.f;
    #pragma unroll
    for (int k = 0; k < 10; ++k) P2 = fmaf(hd[4 + k], W2m[k], P2);
    // P3 = T(w,w,w): canonical combos (pair, last, mult)
    float P3 = 0.f;
    P3 = fmaf(hd[14], 1.f*W2r[0]*w0, P3); P3 = fmaf(hd[15], 3.f*W2r[0]*w1, P3);
    P3 = fmaf(hd[16], 3.f*W2r[0]*w2, P3); P3 = fmaf(hd[17], 3.f*W2r[0]*w3, P3);
    P3 = fmaf(hd[18], 3.f*W2r[1]*w1, P3); P3 = fmaf(hd[19], 6.f*W2r[1]*w2, P3);
    P3 = fmaf(hd[20], 6.f*W2r[1]*w3, P3); P3 = fmaf(hd[21], 3.f*W2r[2]*w2, P3);
    P3 = fmaf(hd[22], 6.f*W2r[2]*w3, P3); P3 = fmaf(hd[23], 3.f*W2r[3]*w3, P3);
    P3 = fmaf(hd[24], 1.f*W2r[4]*w1, P3); P3 = fmaf(hd[25], 3.f*W2r[4]*w2, P3);
    P3 = fmaf(hd[26], 3.f*W2r[4]*w3, P3); P3 = fmaf(hd[27], 3.f*W2r[5]*w2, P3);
    P3 = fmaf(hd[28], 6.f*W2r[5]*w3, P3); P3 = fmaf(hd[29], 3.f*W2r[6]*w3, P3);
    P3 = fmaf(hd[30], 1.f*W2r[7]*w2, P3); P3 = fmaf(hd[31], 3.f*W2r[7]*w3, P3);
    P3 = fmaf(hd[32], 3.f*W2r[8]*w3, P3); P3 = fmaf(hd[33], 1.f*W2r[9]*w3, P3);

    const float C3 = -0.33333334f;
    const float w42 = w4 * w4, w43 = w42 * w4;
    const float tw4_3 = 3.f * w4, tw42_3 = 3.f * w42, n6w4 = -6.f * w4;
    const float P2_3 = 3.f * P2, nP1 = -P1, n3P1 = -3.f * P1, nP3 = -P3;
    const float diag = fmaf(C3, bb * bb * bb, bb);

    const float* rp = hd + HDR + (ihalf * 32) * RECF;   // uniform
    float* ob = out + ((size_t)b * NUM_ENT + ihalf * 32) * (2 * HALF);

    for (int it = 0; it < 32; ++it) {
        const float* r = rp + it * RECF;                // uniform -> s_load
        float e0 = r[0], e1 = r[1], e2 = r[2], e3 = r[3];
        float gw = fmaf(r[4], w0, fmaf(r[5], w1, fmaf(r[6], w2, r[7] * w3)));
        float hw = fmaf(r[8], w0, fmaf(r[9], w1, fmaf(r[10], w2, r[11] * w3)));
        float D1 = r[12], D2 = r[13], D3 = r[14];
        float Gw = 0.f;
        #pragma unroll
        for (int k = 0; k < 10; ++k) Gw = fmaf(r[15 + k], W2m[k], Gw);
        float pi = fmaf(e0, w0, fmaf(e1, w1, fmaf(e2, w2, e3 * w3)));
        float a  = pi + bb;
        float c2 = fmaf(tw4_3, D1, n3P1);
        float c1 = fmaf(tw42_3, D2, P2_3); c1 = fmaf(n6w4, gw, c1);
        float c0 = fmaf(tw4_3, Gw, nP3);
        c0 = fmaf(-tw42_3, hw, c0);
        c0 = fmaf(w43, D3, c0);
        float s3  = fmaf(fmaf(fmaf(64.f, a, c2), a, c1), a, c0);
        float lin = fmaf(w4, D1, fmaf(64.f, a, nP1));
        float rel = fmaf(C3, s3, lin) - diag;
        float xp  = fmaf(e0, q0, fmaf(e1, q1, fmaf(e2, q2, fmaf(e3, q3, bq))));
        ob[it * (2 * HALF) + h]        = tanh5(xp);
        ob[it * (2 * HALF) + HALF + h] = rel;
    }
}

extern "C" void kernel_launch(void* const* d_in, const int* in_sizes, int n_in,
                              void* d_out, int out_size, void* d_ws, size_t ws_size,
                              hipStream_t stream) {
    const float* ctx = (const float*)d_in[0];
    const float* Wp  = (const float*)d_in[1];
    const float* bp  = (const float*)d_in[2];
    const float* Wr  = (const float*)d_in[3];
    const float* br  = (const float*)d_in[4];
    float* out = (float*)d_out;
    float* ws  = (float*)d_ws;   // 512 * 1840 * 4 B = 3.8 MB

    ka_moments<<<dim3(BATCH), dim3(64), 0, stream>>>(ctx, ws);
    kb_out<<<dim3(BATCH), dim3(256), 0, stream>>>(ws, Wp, bp, Wr, br, out);
}